// Round 6
// baseline (559.508 us; speedup 1.0000x reference)
//
#include <hip/hip_runtime.h>
#include <float.h>

// ---------------------------------------------------------------------------
// Fused dual-attention (SCA + SSA).  SEQ=1024, B=8, E=512, H=8, HD=64.
//
//  R11 changes:
//   * proj_v6 REVERTED (compiler never scalarized B; 296 us).
//   * proj_v7: v4 geometry (256 thr, 128x64 tile, grid (64,8,2), 16 waves/CU)
//     but lane=row and B in SGPRs via explicit inline-asm s_load_dwordx16
//     (self-contained asm: 2 loads + s_waitcnt lgkmcnt(0); fma data-depends
//     on asm outputs -> no hoisting hazard). A: [m][k] LDS, 8 ds_read_b128
//     per chunk per lane (vs v4's 96 per wave) -> LDS pipe ~12 us, VALU-bound
//     at ~55 us floor. fp32 chain UNCHANGED (single acc, k ascending 0..511,
//     bias last) -> bit-identical outputs, SSA argmax preserved.
//   * everything else kept from R8 (reg-prefetch gemm/sca/ssa, z-merges).
// ---------------------------------------------------------------------------

namespace {
constexpr int kSeq = 1024;
constexpr int kBsz = 8;
constexpr int kEmb = 512;
constexpr int kHD  = 64;
constexpr float kT1 = 0.6f;
constexpr float kT2 = 0.4f;
constexpr float kScale = 0.125f;   // 1/sqrt(64), exact pow2
constexpr float kMargin = 0.125f;  // >> 6.5-sigma bf16 score error (~0.018)
constexpr int kCap = 256;          // per-wave candidate list capacity
}

typedef short bf16x8 __attribute__((ext_vector_type(8)));
typedef float f32x4  __attribute__((ext_vector_type(4)));
typedef float f32x16 __attribute__((ext_vector_type(16)));

union FragU { uint4 u4; bf16x8 f; uint u[4]; };

__device__ __forceinline__ ushort f2bf(float f) {
  uint u = __float_as_uint(f);
  u += 0x7fff + ((u >> 16) & 1);        // RNE
  return (ushort)(u >> 16);
}
__device__ __forceinline__ uint pack2(float lo, float hi) {
  return (uint)f2bf(lo) | ((uint)f2bf(hi) << 16);
}
__device__ __forceinline__ float bf2f(uint h) {     // h = low 16 bits
  return __uint_as_float(h << 16);
}
__device__ __forceinline__ uint monokey(float v) {
  uint u = __float_as_uint(v);
  return (u & 0x80000000u) ? ~u : (u | 0x80000000u);
}

// ---------------------------------------------------------------------------
// sem_map -> bitmask.  SMASK[t*16 + w] bit j = (SEM[t][w*64+j] >= 0.5)
// ---------------------------------------------------------------------------
__global__ void smask_prep(const float* __restrict__ SEM,
                           unsigned long long* __restrict__ SMASK) {
  const int t = blockIdx.x;
  const int w4 = threadIdx.x >> 6;
  const int lane = threadIdx.x & 63;
#pragma unroll
  for (int i = 0; i < 4; ++i) {
    const int word = (w4 << 2) + i;
    const float v = SEM[t * kSeq + (word << 6) + lane];
    unsigned long long m = __ballot(v >= 0.5f);
    if (lane == 0) SMASK[t * 16 + word] = m;
  }
}

// ---------------------------------------------------------------------------
// fp32 proj GEMM v7 — per-element math byte-identical to R1:
// single accumulator, fma chain k=0..511 ascending, then +bias.
// Block tile 128x64, 256 threads (4 waves). Wave = 64 rows x 32 cols:
// lane owns 1 row; cols iterated in registers (32 acc/lane).
// A via LDS [m][k] stride-36 (8 ds_read_b128 / lane / chunk).
// B via inline-asm s_load_dwordx16 pairs (wave-uniform -> SGPRs); the fma
// consumes B as its scalar operand -> B never touches LDS or vector memory.
// grid (64,8,2): z=0 -> query proj (shadow scaled), z=1 -> key proj.
// Writes head-layout fp32 + bf16 shadow (scaled, RNE).
// ---------------------------------------------------------------------------
__global__ __launch_bounds__(256, 4) void proj_v7(
    const float* __restrict__ Xq, const float* __restrict__ Xk,
    const float* __restrict__ W, const float* __restrict__ bias,
    float* __restrict__ OutQ, float* __restrict__ OutK,
    ushort* __restrict__ ShQ, ushort* __restrict__ ShK)
{
  __shared__ float As[128 * 36];   // [m][k], row stride 36

  const int z = blockIdx.z;
  const float* X = z ? Xk : Xq;
  float* Out = z ? OutK : OutQ;
  ushort* shadow = z ? ShK : ShQ;
  const int woff = z << 9;
  const float sscale = z ? 1.0f : kScale;

  const int mBase = blockIdx.x << 7;    // 128 rows
  const int nBase = blockIdx.y << 6;    // 64 cols
  const int tid = threadIdx.x;
  const int l   = tid & 63;
  const int wu  = __builtin_amdgcn_readfirstlane(tid >> 6);   // wave 0..3
  const int rg  = wu & 1;               // row group (0/1)
  const int cg  = wu >> 1;              // col group (0/1) -> 32 cols
  const int row = (rg << 6) + l;        // lane's m within tile

  const int sr = tid >> 1;              // staging row 0..127
  const int sh = (tid & 1) << 4;        // staging k-half 0/16

  const float* xp = X + (size_t)(mBase + sr) * kEmb + sh;
  const float* wbase = W + (size_t)(woff + nBase + (cg << 5)) * kEmb;

  float acc[32];
#pragma unroll
  for (int c = 0; c < 32; ++c) acc[c] = 0.f;

  // prologue: prefetch chunk-0 staging regs
  float4 st0 = ((const float4*)xp)[0];
  float4 st1 = ((const float4*)xp)[1];
  float4 st2 = ((const float4*)xp)[2];
  float4 st3 = ((const float4*)xp)[3];

  for (int k0 = 0; k0 < kEmb; k0 += 32) {
    __syncthreads();
    {
      float* dst = &As[sr * 36 + sh];
      *(float4*)(dst + 0)  = st0;
      *(float4*)(dst + 4)  = st1;
      *(float4*)(dst + 8)  = st2;
      *(float4*)(dst + 12) = st3;
    }
    __syncthreads();

    // prefetch next chunk's staging regs (hidden under the col loop)
    const int kn = k0 + 32;
    if (kn < kEmb) {
      st0 = ((const float4*)(xp + kn))[0];
      st1 = ((const float4*)(xp + kn))[1];
      st2 = ((const float4*)(xp + kn))[2];
      st3 = ((const float4*)(xp + kn))[3];
    }

    // own row's 32 k values into registers
    float af[32];
#pragma unroll
    for (int j = 0; j < 8; ++j) {
      float4 t = *(const float4*)&As[row * 36 + (j << 2)];
      af[(j << 2) + 0] = t.x;
      af[(j << 2) + 1] = t.y;
      af[(j << 2) + 2] = t.z;
      af[(j << 2) + 3] = t.w;
    }

    // 32 cols: B streamed through SGPRs (scalar pipe), fma per k ascending
#pragma unroll
    for (int c = 0; c < 32; ++c) {
      const float* wcol = wbase + (size_t)c * kEmb + k0;
      f32x16 b0, b1;
      asm volatile(
          "s_load_dwordx16 %0, %2, 0x0\n\t"
          "s_load_dwordx16 %1, %2, 0x40\n\t"
          "s_waitcnt lgkmcnt(0)"
          : "=s"(b0), "=s"(b1)
          : "s"(wcol));
#pragma unroll
      for (int kk = 0; kk < 16; ++kk)
        acc[c] = fmaf(af[kk], b0[kk], acc[c]);
#pragma unroll
      for (int kk = 0; kk < 16; ++kk)
        acc[c] = fmaf(af[16 + kk], b1[kk], acc[c]);
    }
  }

  // epilogue: row m (1 per lane) x 32 cols
  const int m = mBase + row;
#pragma unroll
  for (int c = 0; c < 32; ++c) {
    const int n = nBase + (cg << 5) + c;
    const float v = acc[c] + bias[woff + n];
    const int oi = (((m & 7) << 3) + (n >> 6)) * (kSeq * kHD) +
                   ((m >> 3) << 6) + (n & 63);
    Out[oi] = v;
    shadow[oi] = f2bf(v * sscale);
  }
}

// ---------------------------------------------------------------------------
// bf16 MFMA GEMM: out[m,n] = X[m,:] . W[woff+n,:] + bias.
//  aMode: 0 = fp32 X (converted at LDS-write time); 2 = X already bf16.
//  outMode: 0 = fp32 plain [M][512]; 1 = bf16 headLayout (scaled).
//  grid.z selects X0/X1/X2, woff = woffBase + z*512, Out16 offset z*8MB.
// Tile 128x64, BK=32, 4 waves (2x2), stride-20-uint LDS.
// Register prefetch of the next chunk under the MFMA phase.
// ---------------------------------------------------------------------------
__global__ __launch_bounds__(256, 2) void gemm_bf16(
    const float* __restrict__ X0, const float* __restrict__ X1,
    const float* __restrict__ X2, const ushort* __restrict__ X16,
    const float* __restrict__ W, const float* __restrict__ bias,
    float* __restrict__ OutF, ushort* __restrict__ Out16,
    int woffBase, int aMode, int outMode, float scale0)
{
  __shared__ uint As[128 * 20];
  __shared__ uint Bs[64 * 20];

  const int z = blockIdx.z;
  const float* X = (z == 0) ? X0 : (z == 1) ? X1 : X2;
  const int woff = woffBase + (z << 9);
  const float scale = (z == 0) ? scale0 : 1.0f;
  const size_t zoff = (size_t)z * ((size_t)kSeq * kBsz * kEmb);

  const int mBase = blockIdx.x << 7;
  const int nBase = blockIdx.y << 6;
  const int tid = threadIdx.x;
  const int w = tid >> 6;
  const int l = tid & 63;
  const int l15 = l & 15;
  const int quad = l >> 4;
  const int wm = w & 1, wn = w >> 1;

  const int srow = tid >> 1;         // A staging row 0..127
  const int shalf = tid & 1;

  f32x4 acc[4][2];
#pragma unroll
  for (int mi = 0; mi < 4; ++mi)
#pragma unroll
    for (int ni = 0; ni < 2; ++ni) acc[mi][ni] = (f32x4){0.f, 0.f, 0.f, 0.f};

  // prefetch registers (raw; packed at LDS-write time)
  uint4 qa0, qa1;                      // aMode==2 path
  float4 ra0, ra1, ra2, ra3;           // aMode==0 path
  float4 rb0, rb1, rb2, rb3;           // B (tid<128)

#define GLOAD(kk) do {                                                     \
    if (aMode == 2) {                                                      \
      const uint* src_ = (const uint*)X16 + (size_t)(mBase + srow) * 256 + \
                         ((kk) >> 1) + (shalf << 3);                       \
      qa0 = ((const uint4*)src_)[0];                                       \
      qa1 = ((const uint4*)src_)[1];                                       \
    } else {                                                               \
      const float* xp_ = X + (size_t)(mBase + srow) * kEmb + (kk) +        \
                         (shalf << 4);                                     \
      ra0 = ((const float4*)xp_)[0];                                       \
      ra1 = ((const float4*)xp_)[1];                                       \
      ra2 = ((const float4*)xp_)[2];                                       \
      ra3 = ((const float4*)xp_)[3];                                       \
    }                                                                      \
    if (tid < 128) {                                                       \
      const float* wp_ = W + (size_t)(woff + nBase + srow) * kEmb + (kk) + \
                         (shalf << 4);                                     \
      rb0 = ((const float4*)wp_)[0];                                       \
      rb1 = ((const float4*)wp_)[1];                                       \
      rb2 = ((const float4*)wp_)[2];                                       \
      rb3 = ((const float4*)wp_)[3];                                       \
    }                                                                      \
  } while (0)

  GLOAD(0);

  for (int k0 = 0; k0 < kEmb; k0 += 32) {
    // pack current chunk (vmcnt wait lands here, after previous compute)
    uint4 ah0, ah1, bw0, bw1;
    if (aMode == 2) {
      ah0 = qa0; ah1 = qa1;
    } else {
      ah0 = make_uint4(pack2(ra0.x, ra0.y), pack2(ra0.z, ra0.w),
                       pack2(ra1.x, ra1.y), pack2(ra1.z, ra1.w));
      ah1 = make_uint4(pack2(ra2.x, ra2.y), pack2(ra2.z, ra2.w),
                       pack2(ra3.x, ra3.y), pack2(ra3.z, ra3.w));
    }
    if (tid < 128) {
      bw0 = make_uint4(pack2(rb0.x, rb0.y), pack2(rb0.z, rb0.w),
                       pack2(rb1.x, rb1.y), pack2(rb1.z, rb1.w));
      bw1 = make_uint4(pack2(rb2.x, rb2.y), pack2(rb2.z, rb2.w),
                       pack2(rb3.x, rb3.y), pack2(rb3.z, rb3.w));
    }
    __syncthreads();
    {
      uint* dst = As + srow * 20 + (shalf << 3);
      ((uint4*)dst)[0] = ah0;
      ((uint4*)dst)[1] = ah1;
      if (tid < 128) {
        uint* db = Bs + srow * 20 + (shalf << 3);
        ((uint4*)db)[0] = bw0;
        ((uint4*)db)[1] = bw1;
      }
    }
    __syncthreads();

    // prefetch next chunk under the MFMA phase
    if (k0 + 32 < kEmb) GLOAD(k0 + 32);

    FragU aF[4], bF[2];
#pragma unroll
    for (int ni = 0; ni < 2; ++ni)
      bF[ni].u4 = *(const uint4*)(Bs + ((wn << 5) + (ni << 4) + l15) * 20 + (quad << 2));
#pragma unroll
    for (int mi = 0; mi < 4; ++mi)
      aF[mi].u4 = *(const uint4*)(As + ((wm << 6) + (mi << 4) + l15) * 20 + (quad << 2));
#pragma unroll
    for (int mi = 0; mi < 4; ++mi)
#pragma unroll
      for (int ni = 0; ni < 2; ++ni)
        acc[mi][ni] = __builtin_amdgcn_mfma_f32_16x16x32_bf16(
            aF[mi].f, bF[ni].f, acc[mi][ni], 0, 0, 0);
  }
#undef GLOAD

  // ---- epilogue ----
#pragma unroll
  for (int ni = 0; ni < 2; ++ni) {
    const int n = nBase + (wn << 5) + (ni << 4) + l15;
    const float bv = bias[woff + n];
#pragma unroll
    for (int mi = 0; mi < 4; ++mi) {
#pragma unroll
      for (int r = 0; r < 4; ++r) {
        const int m = mBase + (wm << 6) + (mi << 4) + (quad << 2) + r;
        const float v = acc[mi][ni][r] + bv;
        if (outMode == 0) {
          OutF[(size_t)m * kEmb + n] = v;
        } else {
          const int oi = (((m & 7) << 3) + (n >> 6)) * (kSeq * kHD) +
                         ((m >> 3) << 6) + (n & 63);
          Out16[zoff + oi] = f2bf(v * scale);
        }
      }
    }
  }
}

// ---------------------------------------------------------------------------
// SCA: bf16 Q16 (pre-scaled) / K16 / V16, SMASK bits, MIX16 out.
// K/V tile global loads prefetched one s-tile ahead (regs).
// ---------------------------------------------------------------------------
__global__ __launch_bounds__(256, 4) void sca_mfma2(
    const ushort* __restrict__ Q16, const ushort* __restrict__ K16,
    const ushort* __restrict__ V16,
    const unsigned long long* __restrict__ SMASK,
    ushort* __restrict__ MIX16)
{
  __shared__ uint ks[64 * 36];
  __shared__ uint vt[64 * 36];
  __shared__ uint ps[4][16 * 36];

  const int t0  = blockIdx.x << 6;
  const int bh  = blockIdx.y;
  const int tid = threadIdx.x;
  const int w    = tid >> 6;
  const int l    = tid & 63;
  const int l15  = l & 15;
  const int quad = l >> 4;

  const uint* Qu = (const uint*)Q16 + (size_t)bh * (kSeq * 32);
  const uint* Ku = (const uint*)K16 + (size_t)bh * (kSeq * 32);
  const uint* Vu = (const uint*)V16 + (size_t)bh * (kSeq * 32);

  FragU qf0, qf1;
  {
    const uint* qrow = Qu + (size_t)(t0 + (w << 4) + l15) * 32;
    qf0.u4 = *(const uint4*)(qrow + (quad << 2));
    qf1.u4 = *(const uint4*)(qrow + 16 + (quad << 2));
  }

  f32x4 oacc[4];
#pragma unroll
  for (int nt = 0; nt < 4; ++nt) oacc[nt] = (f32x4){0.f, 0.f, 0.f, 0.f};
  float den[4] = {0.f, 0.f, 0.f, 0.f};

  uint* psw = ps[w];

  // staging thread mappings
  const int sl = tid >> 2, c = tid & 3;    // K tile
  const int p = tid >> 3, c7 = tid & 7;    // V tile

  // prefetch tile 0
  uint4 pk0 = ((const uint4*)(Ku + (size_t)sl * 32 + (c << 3)))[0];
  uint4 pk1 = ((const uint4*)(Ku + (size_t)sl * 32 + (c << 3)))[1];
  uint4 pv0 = *(const uint4*)(Vu + (size_t)(p << 1) * 32 + (c7 << 2));
  uint4 pv1 = *(const uint4*)(Vu + (size_t)(p << 1) * 32 + (c7 << 2) + 32);

  for (int s0 = 0, tile = 0; s0 < kSeq; s0 += 64, ++tile) {
    __syncthreads();
    {   // K tile write: 64 rows x 32 uints
      uint* dst = ks + sl * 36 + (c << 3);
      ((uint4*)dst)[0] = pk0;
      ((uint4*)dst)[1] = pk1;
    }
    {   // V^T tile write from prefetched bf16 V16
      FragU A, B;
      A.u4 = pv0;
      B.u4 = pv1;
      const int Wp = (p + ((c7 & 3) << 2)) & 31;
#pragma unroll
      for (int i = 0; i < 8; ++i) {
        uint ai = (A.u[i >> 1] >> ((i & 1) << 4)) & 0xFFFF;
        uint bi = (B.u[i >> 1] >> ((i & 1) << 4)) & 0xFFFF;
        vt[((c7 << 3) + i) * 36 + Wp] = ai | (bi << 16);
      }
    }
    __syncthreads();

    // prefetch next tile under the compute phase
    if (s0 + 64 < kSeq) {
      const uint* kp = Ku + (size_t)(s0 + 64 + sl) * 32 + (c << 3);
      pk0 = ((const uint4*)kp)[0];
      pk1 = ((const uint4*)kp)[1];
      const uint* va = Vu + (size_t)(s0 + 64 + (p << 1)) * 32 + (c7 << 2);
      pv0 = *(const uint4*)va;
      pv1 = *(const uint4*)(va + 32);
    }

    unsigned long long wv[4];
#pragma unroll
    for (int r = 0; r < 4; ++r)
      wv[r] = SMASK[(size_t)(t0 + (w << 4) + (quad << 2) + r) * 16 + tile];

#pragma unroll
    for (int st = 0; st < 4; ++st) {
      f32x4 sacc = (f32x4){0.f, 0.f, 0.f, 0.f};
      const int srow = (st << 4) + l15;
      FragU kf0, kf1;
      kf0.u4 = *(const uint4*)(ks + srow * 36 + (quad << 2));
      kf1.u4 = *(const uint4*)(ks + srow * 36 + 16 + (quad << 2));
      sacc = __builtin_amdgcn_mfma_f32_16x16x32_bf16(qf0.f, kf0.f, sacc, 0, 0, 0);
      sacc = __builtin_amdgcn_mfma_f32_16x16x32_bf16(qf1.f, kf1.f, sacc, 0, 0, 0);

#pragma unroll
      for (int r = 0; r < 4; ++r) {
        const int trow = (quad << 2) + r;
        const uint bit = (uint)(wv[r] >> ((st << 4) + l15)) & 1u;
        const float val = bit ? __expf(sacc[r]) : 0.f;
        den[r] += val;
        const int W  = (st << 3) + (l15 >> 1);
        const int Wp = (W + (((trow >> 3) & 1) << 3)) & 31;
        ushort* p16 = (ushort*)(psw + trow * 36 + Wp);
        p16[l15 & 1] = f2bf(val);
      }
    }
#pragma unroll
    for (int ch = 0; ch < 2; ++ch) {
      FragU pf;
      const int pw = ((ch << 4) + (quad << 2) + (((l15 >> 3) & 1) << 3)) & 31;
      pf.u4 = *(const uint4*)(psw + l15 * 36 + pw);
#pragma unroll
      for (int nt = 0; nt < 4; ++nt) {
        const int d = (nt << 4) + l15;
        const int vw = ((ch << 4) + (quad << 2) + (((d >> 3) & 3) << 2)) & 31;
        FragU vf;
        vf.u4 = *(const uint4*)(vt + d * 36 + vw);
        oacc[nt] = __builtin_amdgcn_mfma_f32_16x16x32_bf16(pf.f, vf.f, oacc[nt], 0, 0, 0);
      }
    }
  }

#pragma unroll
  for (int r = 0; r < 4; ++r) {
    float d = den[r];
    d += __shfl_xor(d, 1);
    d += __shfl_xor(d, 2);
    d += __shfl_xor(d, 4);
    d += __shfl_xor(d, 8);
    den[r] = kT1 / d;
  }
  const int b = bh >> 3, h = bh & 7;
#pragma unroll
  for (int nt = 0; nt < 4; ++nt) {
#pragma unroll
    for (int r = 0; r < 4; ++r) {
      const int t = t0 + (w << 4) + (quad << 2) + r;
      const int d = (nt << 4) + l15;
      MIX16[(size_t)(t * kBsz + b) * kEmb + (h << 6) + d] =
          f2bf(oacc[nt][r] * den[r]);
    }
  }
}

// ---------------------------------------------------------------------------
// SSA single-pass: bf16 MFMA screen with running cross-lane max; candidates
// within margin recorded to per-wave list (superset-correct); survivors get
// the exact fp32 dot in R1's order; per-row resolve via 64-bit atomicMax.
// K tile prefetched one s-tile ahead.  Block 512 threads.  Grid (8, 64).
// ---------------------------------------------------------------------------
__global__ __launch_bounds__(512, 2) void ssa_v3(
    const ushort* __restrict__ Q16, const ushort* __restrict__ K16,
    const float* __restrict__ Qf, const float* __restrict__ Kf,
    const ushort* __restrict__ V16,
    const unsigned long long* __restrict__ SMASK,
    ushort* __restrict__ MIX16)
{
  __shared__ uint ks[64 * 36];
  __shared__ uint2 list[8][kCap];
  __shared__ float thrL[8][16];
  __shared__ unsigned long long key64L[8][16];
  __shared__ uint cnt[8];

  const int t0  = blockIdx.x << 7;
  const int bh  = blockIdx.y;
  const int tid = threadIdx.x;
  const int w    = tid >> 6;
  const int l    = tid & 63;
  const int l15  = l & 15;
  const int quad = l >> 4;

  if (tid < 8) cnt[tid] = 0;
  if (tid < 128) ((unsigned long long*)key64L)[tid] = 0ull;

  const uint* Qu = (const uint*)Q16 + (size_t)bh * (kSeq * 32);
  const uint* Ku = (const uint*)K16 + (size_t)bh * (kSeq * 32);

  FragU qf0, qf1;
  {
    const uint* qrow = Qu + (size_t)(t0 + (w << 4) + l15) * 32;
    qf0.u4 = *(const uint4*)(qrow + (quad << 2));
    qf1.u4 = *(const uint4*)(qrow + 16 + (quad << 2));
  }

  float m4[4] = {-FLT_MAX, -FLT_MAX, -FLT_MAX, -FLT_MAX};

  const int krow = tid >> 3, kc = tid & 7;   // K staging mapping
  uint4 pk = *(const uint4*)(Ku + (size_t)krow * 32 + (kc << 2));

  for (int s0 = 0, tile = 0; s0 < kSeq; s0 += 64, ++tile) {
    __syncthreads();
    *(uint4*)(ks + krow * 36 + (kc << 2)) = pk;
    __syncthreads();

    if (s0 + 64 < kSeq)
      pk = *(const uint4*)(Ku + (size_t)(s0 + 64 + krow) * 32 + (kc << 2));

    unsigned long long wv[4];
#pragma unroll
    for (int r = 0; r < 4; ++r)
      wv[r] = SMASK[(size_t)(t0 + (w << 4) + (quad << 2) + r) * 16 + tile];

    f32x4 sv[4];
#pragma unroll
    for (int st = 0; st < 4; ++st) {
      f32x4 sacc = (f32x4){0.f, 0.f, 0.f, 0.f};
      const int srow = (st << 4) + l15;
      FragU kf0, kf1;
      kf0.u4 = *(const uint4*)(ks + srow * 36 + (quad << 2));
      kf1.u4 = *(const uint4*)(ks + srow * 36 + 16 + (quad << 2));
      sacc = __builtin_amdgcn_mfma_f32_16x16x32_bf16(qf0.f, kf0.f, sacc, 0, 0, 0);
      sacc = __builtin_amdgcn_mfma_f32_16x16x32_bf16(qf1.f, kf1.f, sacc, 0, 0, 0);
      sv[st] = sacc;
#pragma unroll
      for (int r = 0; r < 4; ++r) {
        const uint bit = (uint)(wv[r] >> ((st << 4) + l15)) & 1u;
        if (bit) m4[r] = fmaxf(m4[r], sacc[r]);
      }
    }
    // cross-lane running max (16 lanes per row share lane bits 0..3)
#pragma unroll
    for (int r = 0; r < 4; ++r) {
      float m = m4[r];
      m = fmaxf(m, __shfl_xor(m, 1));
      m = fmaxf(m, __shfl_xor(m, 2));
      m = fmaxf(m, __shfl_xor(m, 4));
      m = fmaxf(m, __shfl_xor(m, 8));
      m4[r] = m;
    }
    // record candidates vs tightened running threshold (superset of final)
#pragma unroll
    for (int st = 0; st < 4; ++st) {
#pragma unroll
      for (int r = 0; r < 4; ++r) {
        const uint bit = (uint)(wv[r] >> ((st << 4) + l15)) & 1u;
        const float x = sv[st][r];
        if (bit && x >= m4[r] - kMargin) {
          uint idx = atomicAdd(&cnt[w], 1u);
          if (idx < (uint)kCap) {
            const int rowid = (quad << 2) + r;
            const int s = s0 + (st << 4) + l15;
            list[w][idx] = make_uint2(__float_as_uint(x),
                                      ((uint)rowid << 10) | (uint)s);
          }
        }
      }
    }
  }

  // final thresholds to LDS
  if (l15 == 0) {
#pragma unroll
    for (int r = 0; r < 4; ++r) thrL[w][(quad << 2) + r] = m4[r] - kMargin;
  }
  __syncthreads();

  // verify survivors with the EXACT R1-order fp32 dot
  const uint n = min(cnt[w], (uint)kCap);
  const float* Qbf = Qf + (size_t)bh * (kSeq * kHD);
  const float* Kbf = Kf + (size_t)bh * (kSeq * kHD);
  for (uint base = 0; base < n; base += 64) {
    const uint e = base + (uint)l;
    if (e < n) {
      const uint2 ent = list[w][e];
      const uint rowid = ent.y >> 10;
      const uint s = ent.y & 1023u;
      const float xv = __uint_as_float(ent.x);
      if (xv >= thrL[w][rowid]) {
        const int t = t0 + (w << 4) + (int)rowid;
        const float* qe = Qbf + (size_t)t * kHD;
        const float* ke = Kbf + (size_t)s * kHD;
        float p0 = 0.f, p1 = 0.f, p2 = 0.f, p3 = 0.f;
#pragma unroll
        for (int i = 0; i < 16; ++i) {
          float4 qq = *(const float4*)(qe + (i << 2));
          float4 kk = *(const float4*)(ke + (i << 2));
          p0 = fmaf(qq.x, kk.x, p0);
          p1 = fmaf(qq.y, kk.y, p1);
          p2 = fmaf(qq.z, kk.z, p2);
          p3 = fmaf(qq.w, kk.w, p3);
        }
        const float acc = ((p0 + p1) + (p2 + p3)) * kScale;
        const unsigned long long key =
            ((unsigned long long)monokey(acc) << 16) |
            (unsigned long long)(1023u - s);
        atomicMax(&key64L[w][rowid], key);
      }
    }
  }
  __syncthreads();

  // gather v16[argmax] into MIX16
  const int b = bh >> 3, h = bh & 7;
  const uint* Vu = (const uint*)V16 + (size_t)bh * (kSeq * 32);
#pragma unroll
  for (int r = 0; r < 4; ++r) {
    const int rowid = (quad << 2) + r;
    const unsigned long long key = key64L[w][rowid];
    const uint s = 1023u - (uint)(key & 0xFFFFull);
    const uint2 vv = *(const uint2*)(Vu + (size_t)s * 32 + (l15 << 1));
    const int t = t0 + (w << 4) + rowid;
    uint* op = (uint*)MIX16 + ((size_t)(t * kBsz + b) * kEmb + (h << 6)) / 2 + (l15 << 1);
    uint2 o = *(uint2*)op;
    float o0 = bf2f(o.x & 0xFFFF) + kT2 * bf2f(vv.x & 0xFFFF);
    float o1 = bf2f(o.x >> 16)    + kT2 * bf2f(vv.x >> 16);
    float o2 = bf2f(o.y & 0xFFFF) + kT2 * bf2f(vv.y & 0xFFFF);
    float o3 = bf2f(o.y >> 16)    + kT2 * bf2f(vv.y >> 16);
    *(uint2*)op = make_uint2(pack2(o0, o1), pack2(o2, o3));
  }
}

extern "C" void kernel_launch(void* const* d_in, const int* in_sizes, int n_in,
                              void* d_out, int out_size, void* d_ws, size_t ws_size,
                              hipStream_t stream) {
  const float* query  = (const float*)d_in[0];
  const float* key    = (const float*)d_in[1];
  const float* value  = (const float*)d_in[2];
  const float* qsem   = (const float*)d_in[3];
  const float* ksem   = (const float*)d_in[4];
  const float* semmap = (const float*)d_in[5];
  const float* Wi     = (const float*)d_in[6];
  const float* bi     = (const float*)d_in[7];
  const float* Wo     = (const float*)d_in[8];
  const float* bo     = (const float*)d_in[9];
  float* out = (float*)d_out;

  char* ws = (char*)d_ws;
  unsigned long long* SMASK = (unsigned long long*)ws;          ws += 1024 * 16 * 8;
  ushort* Q16  = (ushort*)ws;  ws += (size_t)64 * kSeq * kHD * 2;   // 8 MB
  ushort* K16  = (ushort*)ws;  ws += (size_t)64 * kSeq * kHD * 2;   // 8 MB
  ushort* V16  = (ushort*)ws;  ws += (size_t)64 * kSeq * kHD * 2;   // 8 MB
  ushort* MIX16 = (ushort*)ws; ws += (size_t)kSeq * kBsz * kEmb * 2; // 8 MB
  float* P1 = (float*)ws;      ws += (size_t)64 * kSeq * kHD * 4;   // 16 MB
  float* P0 = out;   // d_out is dead until the final GEMM: use as fp32 Q proj

  const dim3 gp(64, 8, 2);   // fp32 proj grid (128x64 tiles, z = q/k)
  const dim3 g3(64, 8, 3);   // bf16 gemm grid, z = qsem/ksem/value
  const dim3 gb(64, 8);      // bf16 gemm grid (out proj)
  const dim3 gs(16, 64);     // sca: t-tile x bh
  const dim3 gv(8, 64);      // ssa: 128-row t-tile x bh

  smask_prep<<<1024, 256, 0, stream>>>(semmap, SMASK);
  // SCA projections (bf16 MFMA), merged q/k/v in one launch
  gemm_bf16<<<g3, 256, 0, stream>>>(qsem, ksem, value, nullptr, Wi, bi,
                                    nullptr, Q16, 0, 0, 1, kScale);
  // SCA attention -> MIX16 = bf16(T1 * o_sca)
  sca_mfma2<<<gs, 256, 0, stream>>>(Q16, K16, V16, SMASK, MIX16);
  // SSA projections: fp32 math identical to R1 + bf16 shadows (merged q/k)
  proj_v7<<<gp, 256, 0, stream>>>(query, key, Wi, bi, P0, P1, Q16, K16);
  // SSA screen+verify -> MIX16 += bf16(T2 * v[argmax])
  ssa_v3<<<gv, 512, 0, stream>>>(Q16, K16, P0, P1, V16, SMASK, MIX16);
  // Out projection (reads bf16 MIX16 directly)
  gemm_bf16<<<gb, 256, 0, stream>>>(nullptr, nullptr, nullptr, MIX16, Wo, bo,
                                    out, nullptr, 0, 2, 0, 1.0f);
}

// Round 7
// 407.112 us; speedup vs baseline: 1.3743x; 1.3743x over previous
//
#include <hip/hip_runtime.h>
#include <float.h>

// ---------------------------------------------------------------------------
// Fused dual-attention (SCA + SSA).  SEQ=1024, B=8, E=512, H=8, HD=64.
//
//  R12 changes:
//   * proj_v7 REVERTED (acc spilled to scratch: WRITE_SIZE 440 MB, 290 us).
//     proj_v4 restored (R8 harness-verified, 129.5 us). LDS model closed:
//     fma/read = 4rc/(r+c); 8x4 -> 123 us floor (measured 129.5), 8x8 ->
//     82 us floor but only 2 waves/SIMD (measured 160). v4 is the floor
//     for this structure; fp32 chain bit-identical to R1.
//   * gemm_bf16: __launch_bounds__(256,2) -> (256,4). Was 2 blocks/CU
//     (2 waves/SIMD) with 2 barriers per K-step; reg demand ~110 fits 128.
//   * ssa_v3: __launch_bounds__(512,2) -> (512,4). Was 1 block/CU; LDS
//     27.2 KB x2 = 54 KB fits; regs ~70 << 128.
// ---------------------------------------------------------------------------

namespace {
constexpr int kSeq = 1024;
constexpr int kBsz = 8;
constexpr int kEmb = 512;
constexpr int kHD  = 64;
constexpr float kT1 = 0.6f;
constexpr float kT2 = 0.4f;
constexpr float kScale = 0.125f;   // 1/sqrt(64), exact pow2
constexpr float kMargin = 0.125f;  // >> 6.5-sigma bf16 score error (~0.018)
constexpr int kCap = 256;          // per-wave candidate list capacity
}

typedef short bf16x8 __attribute__((ext_vector_type(8)));
typedef float f32x4  __attribute__((ext_vector_type(4)));

union FragU { uint4 u4; bf16x8 f; uint u[4]; };

__device__ __forceinline__ ushort f2bf(float f) {
  uint u = __float_as_uint(f);
  u += 0x7fff + ((u >> 16) & 1);        // RNE
  return (ushort)(u >> 16);
}
__device__ __forceinline__ uint pack2(float lo, float hi) {
  return (uint)f2bf(lo) | ((uint)f2bf(hi) << 16);
}
__device__ __forceinline__ float bf2f(uint h) {     // h = low 16 bits
  return __uint_as_float(h << 16);
}
__device__ __forceinline__ uint monokey(float v) {
  uint u = __float_as_uint(v);
  return (u & 0x80000000u) ? ~u : (u | 0x80000000u);
}

// ---------------------------------------------------------------------------
// sem_map -> bitmask.  SMASK[t*16 + w] bit j = (SEM[t][w*64+j] >= 0.5)
// ---------------------------------------------------------------------------
__global__ void smask_prep(const float* __restrict__ SEM,
                           unsigned long long* __restrict__ SMASK) {
  const int t = blockIdx.x;
  const int w4 = threadIdx.x >> 6;
  const int lane = threadIdx.x & 63;
#pragma unroll
  for (int i = 0; i < 4; ++i) {
    const int word = (w4 << 2) + i;
    const float v = SEM[t * kSeq + (word << 6) + lane];
    unsigned long long m = __ballot(v >= 0.5f);
    if (lane == 0) SMASK[t * 16 + word] = m;
  }
}

// ---------------------------------------------------------------------------
// fp32 proj GEMM v4 — per-element math byte-identical to R1:
// single accumulator, fma chain k=0..511 ascending, then +bias.
// Tile 128x64, 256 threads, per-thread 8 rows x 4 cols, BK=32.
// Register prefetch: chunk k0+32 loads issued after the LDS-write barrier
// of chunk k0 so the 1024-fma compute phase hides the global latency.
// grid.z: z=0 -> query proj (woff 0, shadow scaled), z=1 -> key proj.
// Writes head-layout fp32 + bf16 shadow (scaled, RNE).
// ---------------------------------------------------------------------------
__global__ __launch_bounds__(256, 4) void proj_v4(
    const float* __restrict__ Xq, const float* __restrict__ Xk,
    const float* __restrict__ W, const float* __restrict__ bias,
    float* __restrict__ OutQ, float* __restrict__ OutK,
    ushort* __restrict__ ShQ, ushort* __restrict__ ShK)
{
  __shared__ float As[32 * 132];   // [k][m], 128 m + pad 4
  __shared__ float Bs[32 * 68];    // [k][n], 64 n + pad 4

  const int z = blockIdx.z;
  const float* X = z ? Xk : Xq;
  float* Out = z ? OutK : OutQ;
  ushort* shadow = z ? ShK : ShQ;
  const int woff = z << 9;
  const float sscale = z ? 1.0f : kScale;

  const int mBase = blockIdx.x << 7;
  const int nBase = blockIdx.y << 6;
  const int tid = threadIdx.x;
  const int tx = tid & 15;        // col group: n = nBase + tx*4 + j
  const int my = tid >> 4;        // row group: m = mBase + my*8 + i
  const int ar = tid >> 1, ah = (tid & 1) << 4;   // A staging: row, k-half
  const int br = tid >> 2, bk = (tid & 3) << 3;   // B staging: row, k-oct

  float acc[8][4];
#pragma unroll
  for (int i = 0; i < 8; ++i)
#pragma unroll
    for (int j = 0; j < 4; ++j) acc[i][j] = 0.f;

  const float* xp = X + (size_t)(mBase + ar) * kEmb + ah;
  const float* wp = W + (size_t)(woff + nBase + br) * kEmb + bk;

  // prologue: load chunk 0 into registers
  float4 a0 = ((const float4*)xp)[0];
  float4 a1 = ((const float4*)xp)[1];
  float4 a2 = ((const float4*)xp)[2];
  float4 a3 = ((const float4*)xp)[3];
  float4 b0 = ((const float4*)wp)[0];
  float4 b1 = ((const float4*)wp)[1];

  for (int k0 = 0; k0 < kEmb; k0 += 32) {
    __syncthreads();
    {
      float av[16] = {a0.x, a0.y, a0.z, a0.w, a1.x, a1.y, a1.z, a1.w,
                      a2.x, a2.y, a2.z, a2.w, a3.x, a3.y, a3.z, a3.w};
#pragma unroll
      for (int i = 0; i < 16; ++i) As[(ah + i) * 132 + ar] = av[i];
      float bv[8] = {b0.x, b0.y, b0.z, b0.w, b1.x, b1.y, b1.z, b1.w};
#pragma unroll
      for (int i = 0; i < 8; ++i) Bs[(bk + i) * 68 + br] = bv[i];
    }
    __syncthreads();

    // prefetch next chunk (hidden under the fma phase below)
    const int kn = k0 + 32;
    if (kn < kEmb) {
      a0 = ((const float4*)(xp + kn))[0];
      a1 = ((const float4*)(xp + kn))[1];
      a2 = ((const float4*)(xp + kn))[2];
      a3 = ((const float4*)(xp + kn))[3];
      b0 = ((const float4*)(wp + kn))[0];
      b1 = ((const float4*)(wp + kn))[1];
    }

#pragma unroll 8
    for (int k = 0; k < 32; ++k) {
      float4 A0 = *(const float4*)&As[k * 132 + (my << 3)];
      float4 A1 = *(const float4*)&As[k * 132 + (my << 3) + 4];
      float4 Bv = *(const float4*)&Bs[k * 68 + (tx << 2)];
      float aa[8] = {A0.x, A0.y, A0.z, A0.w, A1.x, A1.y, A1.z, A1.w};
      float bb[4] = {Bv.x, Bv.y, Bv.z, Bv.w};
#pragma unroll
      for (int i = 0; i < 8; ++i)
#pragma unroll
        for (int j = 0; j < 4; ++j)
          acc[i][j] = fmaf(aa[i], bb[j], acc[i][j]);
    }
  }

#pragma unroll
  for (int i = 0; i < 8; ++i) {
    const int m = mBase + (my << 3) + i;
#pragma unroll
    for (int j = 0; j < 4; ++j) {
      const int n = nBase + (tx << 2) + j;
      const float v = acc[i][j] + bias[woff + n];
      const int oi = (((m & 7) << 3) + (n >> 6)) * (kSeq * kHD) +
                     ((m >> 3) << 6) + (n & 63);
      Out[oi] = v;
      shadow[oi] = f2bf(v * sscale);
    }
  }
}

// ---------------------------------------------------------------------------
// bf16 MFMA GEMM: out[m,n] = X[m,:] . W[woff+n,:] + bias.
//  aMode: 0 = fp32 X (converted at LDS-write time); 2 = X already bf16.
//  outMode: 0 = fp32 plain [M][512]; 1 = bf16 headLayout (scaled).
//  grid.z selects X0/X1/X2, woff = woffBase + z*512, Out16 offset z*8MB.
// Tile 128x64, BK=32, 4 waves (2x2), stride-20-uint LDS.
// Register prefetch of the next chunk under the MFMA phase.
// (256,4): 4 blocks/CU — was 2 blocks/CU (2 waves/SIMD) in R8.
// ---------------------------------------------------------------------------
__global__ __launch_bounds__(256, 4) void gemm_bf16(
    const float* __restrict__ X0, const float* __restrict__ X1,
    const float* __restrict__ X2, const ushort* __restrict__ X16,
    const float* __restrict__ W, const float* __restrict__ bias,
    float* __restrict__ OutF, ushort* __restrict__ Out16,
    int woffBase, int aMode, int outMode, float scale0)
{
  __shared__ uint As[128 * 20];
  __shared__ uint Bs[64 * 20];

  const int z = blockIdx.z;
  const float* X = (z == 0) ? X0 : (z == 1) ? X1 : X2;
  const int woff = woffBase + (z << 9);
  const float scale = (z == 0) ? scale0 : 1.0f;
  const size_t zoff = (size_t)z * ((size_t)kSeq * kBsz * kEmb);

  const int mBase = blockIdx.x << 7;
  const int nBase = blockIdx.y << 6;
  const int tid = threadIdx.x;
  const int w = tid >> 6;
  const int l = tid & 63;
  const int l15 = l & 15;
  const int quad = l >> 4;
  const int wm = w & 1, wn = w >> 1;

  const int srow = tid >> 1;         // A staging row 0..127
  const int shalf = tid & 1;

  f32x4 acc[4][2];
#pragma unroll
  for (int mi = 0; mi < 4; ++mi)
#pragma unroll
    for (int ni = 0; ni < 2; ++ni) acc[mi][ni] = (f32x4){0.f, 0.f, 0.f, 0.f};

  // prefetch registers (raw; packed at LDS-write time)
  uint4 qa0, qa1;                      // aMode==2 path
  float4 ra0, ra1, ra2, ra3;           // aMode==0 path
  float4 rb0, rb1, rb2, rb3;           // B (tid<128)

#define GLOAD(kk) do {                                                     \
    if (aMode == 2) {                                                      \
      const uint* src_ = (const uint*)X16 + (size_t)(mBase + srow) * 256 + \
                         ((kk) >> 1) + (shalf << 3);                       \
      qa0 = ((const uint4*)src_)[0];                                       \
      qa1 = ((const uint4*)src_)[1];                                       \
    } else {                                                               \
      const float* xp_ = X + (size_t)(mBase + srow) * kEmb + (kk) +        \
                         (shalf << 4);                                     \
      ra0 = ((const float4*)xp_)[0];                                       \
      ra1 = ((const float4*)xp_)[1];                                       \
      ra2 = ((const float4*)xp_)[2];                                       \
      ra3 = ((const float4*)xp_)[3];                                       \
    }                                                                      \
    if (tid < 128) {                                                       \
      const float* wp_ = W + (size_t)(woff + nBase + srow) * kEmb + (kk) + \
                         (shalf << 4);                                     \
      rb0 = ((const float4*)wp_)[0];                                       \
      rb1 = ((const float4*)wp_)[1];                                       \
      rb2 = ((const float4*)wp_)[2];                                       \
      rb3 = ((const float4*)wp_)[3];                                       \
    }                                                                      \
  } while (0)

  GLOAD(0);

  for (int k0 = 0; k0 < kEmb; k0 += 32) {
    // pack current chunk (vmcnt wait lands here, after previous compute)
    uint4 ah0, ah1, bw0, bw1;
    if (aMode == 2) {
      ah0 = qa0; ah1 = qa1;
    } else {
      ah0 = make_uint4(pack2(ra0.x, ra0.y), pack2(ra0.z, ra0.w),
                       pack2(ra1.x, ra1.y), pack2(ra1.z, ra1.w));
      ah1 = make_uint4(pack2(ra2.x, ra2.y), pack2(ra2.z, ra2.w),
                       pack2(ra3.x, ra3.y), pack2(ra3.z, ra3.w));
    }
    if (tid < 128) {
      bw0 = make_uint4(pack2(rb0.x, rb0.y), pack2(rb0.z, rb0.w),
                       pack2(rb1.x, rb1.y), pack2(rb1.z, rb1.w));
      bw1 = make_uint4(pack2(rb2.x, rb2.y), pack2(rb2.z, rb2.w),
                       pack2(rb3.x, rb3.y), pack2(rb3.z, rb3.w));
    }
    __syncthreads();
    {
      uint* dst = As + srow * 20 + (shalf << 3);
      ((uint4*)dst)[0] = ah0;
      ((uint4*)dst)[1] = ah1;
      if (tid < 128) {
        uint* db = Bs + srow * 20 + (shalf << 3);
        ((uint4*)db)[0] = bw0;
        ((uint4*)db)[1] = bw1;
      }
    }
    __syncthreads();

    // prefetch next chunk under the MFMA phase
    if (k0 + 32 < kEmb) GLOAD(k0 + 32);

    FragU aF[4], bF[2];
#pragma unroll
    for (int ni = 0; ni < 2; ++ni)
      bF[ni].u4 = *(const uint4*)(Bs + ((wn << 5) + (ni << 4) + l15) * 20 + (quad << 2));
#pragma unroll
    for (int mi = 0; mi < 4; ++mi)
      aF[mi].u4 = *(const uint4*)(As + ((wm << 6) + (mi << 4) + l15) * 20 + (quad << 2));
#pragma unroll
    for (int mi = 0; mi < 4; ++mi)
#pragma unroll
      for (int ni = 0; ni < 2; ++ni)
        acc[mi][ni] = __builtin_amdgcn_mfma_f32_16x16x32_bf16(
            aF[mi].f, bF[ni].f, acc[mi][ni], 0, 0, 0);
  }
#undef GLOAD

  // ---- epilogue ----
#pragma unroll
  for (int ni = 0; ni < 2; ++ni) {
    const int n = nBase + (wn << 5) + (ni << 4) + l15;
    const float bv = bias[woff + n];
#pragma unroll
    for (int mi = 0; mi < 4; ++mi) {
#pragma unroll
      for (int r = 0; r < 4; ++r) {
        const int m = mBase + (wm << 6) + (mi << 4) + (quad << 2) + r;
        const float v = acc[mi][ni][r] + bv;
        if (outMode == 0) {
          OutF[(size_t)m * kEmb + n] = v;
        } else {
          const int oi = (((m & 7) << 3) + (n >> 6)) * (kSeq * kHD) +
                         ((m >> 3) << 6) + (n & 63);
          Out16[zoff + oi] = f2bf(v * scale);
        }
      }
    }
  }
}

// ---------------------------------------------------------------------------
// SCA: bf16 Q16 (pre-scaled) / K16 / V16, SMASK bits, MIX16 out.
// K/V tile global loads prefetched one s-tile ahead (regs).
// ---------------------------------------------------------------------------
__global__ __launch_bounds__(256, 4) void sca_mfma2(
    const ushort* __restrict__ Q16, const ushort* __restrict__ K16,
    const ushort* __restrict__ V16,
    const unsigned long long* __restrict__ SMASK,
    ushort* __restrict__ MIX16)
{
  __shared__ uint ks[64 * 36];
  __shared__ uint vt[64 * 36];
  __shared__ uint ps[4][16 * 36];

  const int t0  = blockIdx.x << 6;
  const int bh  = blockIdx.y;
  const int tid = threadIdx.x;
  const int w    = tid >> 6;
  const int l    = tid & 63;
  const int l15  = l & 15;
  const int quad = l >> 4;

  const uint* Qu = (const uint*)Q16 + (size_t)bh * (kSeq * 32);
  const uint* Ku = (const uint*)K16 + (size_t)bh * (kSeq * 32);
  const uint* Vu = (const uint*)V16 + (size_t)bh * (kSeq * 32);

  FragU qf0, qf1;
  {
    const uint* qrow = Qu + (size_t)(t0 + (w << 4) + l15) * 32;
    qf0.u4 = *(const uint4*)(qrow + (quad << 2));
    qf1.u4 = *(const uint4*)(qrow + 16 + (quad << 2));
  }

  f32x4 oacc[4];
#pragma unroll
  for (int nt = 0; nt < 4; ++nt) oacc[nt] = (f32x4){0.f, 0.f, 0.f, 0.f};
  float den[4] = {0.f, 0.f, 0.f, 0.f};

  uint* psw = ps[w];

  // staging thread mappings
  const int sl = tid >> 2, c = tid & 3;    // K tile
  const int p = tid >> 3, c7 = tid & 7;    // V tile

  // prefetch tile 0
  uint4 pk0 = ((const uint4*)(Ku + (size_t)sl * 32 + (c << 3)))[0];
  uint4 pk1 = ((const uint4*)(Ku + (size_t)sl * 32 + (c << 3)))[1];
  uint4 pv0 = *(const uint4*)(Vu + (size_t)(p << 1) * 32 + (c7 << 2));
  uint4 pv1 = *(const uint4*)(Vu + (size_t)(p << 1) * 32 + (c7 << 2) + 32);

  for (int s0 = 0, tile = 0; s0 < kSeq; s0 += 64, ++tile) {
    __syncthreads();
    {   // K tile write: 64 rows x 32 uints
      uint* dst = ks + sl * 36 + (c << 3);
      ((uint4*)dst)[0] = pk0;
      ((uint4*)dst)[1] = pk1;
    }
    {   // V^T tile write from prefetched bf16 V16
      FragU A, B;
      A.u4 = pv0;
      B.u4 = pv1;
      const int Wp = (p + ((c7 & 3) << 2)) & 31;
#pragma unroll
      for (int i = 0; i < 8; ++i) {
        uint ai = (A.u[i >> 1] >> ((i & 1) << 4)) & 0xFFFF;
        uint bi = (B.u[i >> 1] >> ((i & 1) << 4)) & 0xFFFF;
        vt[((c7 << 3) + i) * 36 + Wp] = ai | (bi << 16);
      }
    }
    __syncthreads();

    // prefetch next tile under the compute phase
    if (s0 + 64 < kSeq) {
      const uint* kp = Ku + (size_t)(s0 + 64 + sl) * 32 + (c << 3);
      pk0 = ((const uint4*)kp)[0];
      pk1 = ((const uint4*)kp)[1];
      const uint* va = Vu + (size_t)(s0 + 64 + (p << 1)) * 32 + (c7 << 2);
      pv0 = *(const uint4*)va;
      pv1 = *(const uint4*)(va + 32);
    }

    unsigned long long wv[4];
#pragma unroll
    for (int r = 0; r < 4; ++r)
      wv[r] = SMASK[(size_t)(t0 + (w << 4) + (quad << 2) + r) * 16 + tile];

#pragma unroll
    for (int st = 0; st < 4; ++st) {
      f32x4 sacc = (f32x4){0.f, 0.f, 0.f, 0.f};
      const int srow = (st << 4) + l15;
      FragU kf0, kf1;
      kf0.u4 = *(const uint4*)(ks + srow * 36 + (quad << 2));
      kf1.u4 = *(const uint4*)(ks + srow * 36 + 16 + (quad << 2));
      sacc = __builtin_amdgcn_mfma_f32_16x16x32_bf16(qf0.f, kf0.f, sacc, 0, 0, 0);
      sacc = __builtin_amdgcn_mfma_f32_16x16x32_bf16(qf1.f, kf1.f, sacc, 0, 0, 0);

#pragma unroll
      for (int r = 0; r < 4; ++r) {
        const int trow = (quad << 2) + r;
        const uint bit = (uint)(wv[r] >> ((st << 4) + l15)) & 1u;
        const float val = bit ? __expf(sacc[r]) : 0.f;
        den[r] += val;
        const int W  = (st << 3) + (l15 >> 1);
        const int Wp = (W + (((trow >> 3) & 1) << 3)) & 31;
        ushort* p16 = (ushort*)(psw + trow * 36 + Wp);
        p16[l15 & 1] = f2bf(val);
      }
    }
#pragma unroll
    for (int ch = 0; ch < 2; ++ch) {
      FragU pf;
      const int pw = ((ch << 4) + (quad << 2) + (((l15 >> 3) & 1) << 3)) & 31;
      pf.u4 = *(const uint4*)(psw + l15 * 36 + pw);
#pragma unroll
      for (int nt = 0; nt < 4; ++nt) {
        const int d = (nt << 4) + l15;
        const int vw = ((ch << 4) + (quad << 2) + (((d >> 3) & 3) << 2)) & 31;
        FragU vf;
        vf.u4 = *(const uint4*)(vt + d * 36 + vw);
        oacc[nt] = __builtin_amdgcn_mfma_f32_16x16x32_bf16(pf.f, vf.f, oacc[nt], 0, 0, 0);
      }
    }
  }

#pragma unroll
  for (int r = 0; r < 4; ++r) {
    float d = den[r];
    d += __shfl_xor(d, 1);
    d += __shfl_xor(d, 2);
    d += __shfl_xor(d, 4);
    d += __shfl_xor(d, 8);
    den[r] = kT1 / d;
  }
  const int b = bh >> 3, h = bh & 7;
#pragma unroll
  for (int nt = 0; nt < 4; ++nt) {
#pragma unroll
    for (int r = 0; r < 4; ++r) {
      const int t = t0 + (w << 4) + (quad << 2) + r;
      const int d = (nt << 4) + l15;
      MIX16[(size_t)(t * kBsz + b) * kEmb + (h << 6) + d] =
          f2bf(oacc[nt][r] * den[r]);
    }
  }
}

// ---------------------------------------------------------------------------
// SSA single-pass: bf16 MFMA screen with running cross-lane max; candidates
// within margin recorded to per-wave list (superset-correct); survivors get
// the exact fp32 dot in R1's order; per-row resolve via 64-bit atomicMax.
// K tile prefetched one s-tile ahead.  Block 512 threads.  Grid (8, 64).
// (512,4): 2 blocks/CU — was 1 block/CU (2 waves/SIMD) in R8.
// ---------------------------------------------------------------------------
__global__ __launch_bounds__(512, 4) void ssa_v3(
    const ushort* __restrict__ Q16, const ushort* __restrict__ K16,
    const float* __restrict__ Qf, const float* __restrict__ Kf,
    const ushort* __restrict__ V16,
    const unsigned long long* __restrict__ SMASK,
    ushort* __restrict__ MIX16)
{
  __shared__ uint ks[64 * 36];
  __shared__ uint2 list[8][kCap];
  __shared__ float thrL[8][16];
  __shared__ unsigned long long key64L[8][16];
  __shared__ uint cnt[8];

  const int t0  = blockIdx.x << 7;
  const int bh  = blockIdx.y;
  const int tid = threadIdx.x;
  const int w    = tid >> 6;
  const int l    = tid & 63;
  const int l15  = l & 15;
  const int quad = l >> 4;

  if (tid < 8) cnt[tid] = 0;
  if (tid < 128) ((unsigned long long*)key64L)[tid] = 0ull;

  const uint* Qu = (const uint*)Q16 + (size_t)bh * (kSeq * 32);
  const uint* Ku = (const uint*)K16 + (size_t)bh * (kSeq * 32);

  FragU qf0, qf1;
  {
    const uint* qrow = Qu + (size_t)(t0 + (w << 4) + l15) * 32;
    qf0.u4 = *(const uint4*)(qrow + (quad << 2));
    qf1.u4 = *(const uint4*)(qrow + 16 + (quad << 2));
  }

  float m4[4] = {-FLT_MAX, -FLT_MAX, -FLT_MAX, -FLT_MAX};

  const int krow = tid >> 3, kc = tid & 7;   // K staging mapping
  uint4 pk = *(const uint4*)(Ku + (size_t)krow * 32 + (kc << 2));

  for (int s0 = 0, tile = 0; s0 < kSeq; s0 += 64, ++tile) {
    __syncthreads();
    *(uint4*)(ks + krow * 36 + (kc << 2)) = pk;
    __syncthreads();

    if (s0 + 64 < kSeq)
      pk = *(const uint4*)(Ku + (size_t)(s0 + 64 + krow) * 32 + (kc << 2));

    unsigned long long wv[4];
#pragma unroll
    for (int r = 0; r < 4; ++r)
      wv[r] = SMASK[(size_t)(t0 + (w << 4) + (quad << 2) + r) * 16 + tile];

    f32x4 sv[4];
#pragma unroll
    for (int st = 0; st < 4; ++st) {
      f32x4 sacc = (f32x4){0.f, 0.f, 0.f, 0.f};
      const int srow = (st << 4) + l15;
      FragU kf0, kf1;
      kf0.u4 = *(const uint4*)(ks + srow * 36 + (quad << 2));
      kf1.u4 = *(const uint4*)(ks + srow * 36 + 16 + (quad << 2));
      sacc = __builtin_amdgcn_mfma_f32_16x16x32_bf16(qf0.f, kf0.f, sacc, 0, 0, 0);
      sacc = __builtin_amdgcn_mfma_f32_16x16x32_bf16(qf1.f, kf1.f, sacc, 0, 0, 0);
      sv[st] = sacc;
#pragma unroll
      for (int r = 0; r < 4; ++r) {
        const uint bit = (uint)(wv[r] >> ((st << 4) + l15)) & 1u;
        if (bit) m4[r] = fmaxf(m4[r], sacc[r]);
      }
    }
    // cross-lane running max (16 lanes per row share lane bits 0..3)
#pragma unroll
    for (int r = 0; r < 4; ++r) {
      float m = m4[r];
      m = fmaxf(m, __shfl_xor(m, 1));
      m = fmaxf(m, __shfl_xor(m, 2));
      m = fmaxf(m, __shfl_xor(m, 4));
      m = fmaxf(m, __shfl_xor(m, 8));
      m4[r] = m;
    }
    // record candidates vs tightened running threshold (superset of final)
#pragma unroll
    for (int st = 0; st < 4; ++st) {
#pragma unroll
      for (int r = 0; r < 4; ++r) {
        const uint bit = (uint)(wv[r] >> ((st << 4) + l15)) & 1u;
        const float x = sv[st][r];
        if (bit && x >= m4[r] - kMargin) {
          uint idx = atomicAdd(&cnt[w], 1u);
          if (idx < (uint)kCap) {
            const int rowid = (quad << 2) + r;
            const int s = s0 + (st << 4) + l15;
            list[w][idx] = make_uint2(__float_as_uint(x),
                                      ((uint)rowid << 10) | (uint)s);
          }
        }
      }
    }
  }

  // final thresholds to LDS
  if (l15 == 0) {
#pragma unroll
    for (int r = 0; r < 4; ++r) thrL[w][(quad << 2) + r] = m4[r] - kMargin;
  }
  __syncthreads();

  // verify survivors with the EXACT R1-order fp32 dot
  const uint n = min(cnt[w], (uint)kCap);
  const float* Qbf = Qf + (size_t)bh * (kSeq * kHD);
  const float* Kbf = Kf + (size_t)bh * (kSeq * kHD);
  for (uint base = 0; base < n; base += 64) {
    const uint e = base + (uint)l;
    if (e < n) {
      const uint2 ent = list[w][e];
      const uint rowid = ent.y >> 10;
      const uint s = ent.y & 1023u;
      const float xv = __uint_as_float(ent.x);
      if (xv >= thrL[w][rowid]) {
        const int t = t0 + (w << 4) + (int)rowid;
        const float* qe = Qbf + (size_t)t * kHD;
        const float* ke = Kbf + (size_t)s * kHD;
        float p0 = 0.f, p1 = 0.f, p2 = 0.f, p3 = 0.f;
#pragma unroll
        for (int i = 0; i < 16; ++i) {
          float4 qq = *(const float4*)(qe + (i << 2));
          float4 kk = *(const float4*)(ke + (i << 2));
          p0 = fmaf(qq.x, kk.x, p0);
          p1 = fmaf(qq.y, kk.y, p1);
          p2 = fmaf(qq.z, kk.z, p2);
          p3 = fmaf(qq.w, kk.w, p3);
        }
        const float acc = ((p0 + p1) + (p2 + p3)) * kScale;
        const unsigned long long key =
            ((unsigned long long)monokey(acc) << 16) |
            (unsigned long long)(1023u - s);
        atomicMax(&key64L[w][rowid], key);
      }
    }
  }
  __syncthreads();

  // gather v16[argmax] into MIX16
  const int b = bh >> 3, h = bh & 7;
  const uint* Vu = (const uint*)V16 + (size_t)bh * (kSeq * 32);
#pragma unroll
  for (int r = 0; r < 4; ++r) {
    const int rowid = (quad << 2) + r;
    const unsigned long long key = key64L[w][rowid];
    const uint s = 1023u - (uint)(key & 0xFFFFull);
    const uint2 vv = *(const uint2*)(Vu + (size_t)s * 32 + (l15 << 1));
    const int t = t0 + (w << 4) + rowid;
    uint* op = (uint*)MIX16 + ((size_t)(t * kBsz + b) * kEmb + (h << 6)) / 2 + (l15 << 1);
    uint2 o = *(uint2*)op;
    float o0 = bf2f(o.x & 0xFFFF) + kT2 * bf2f(vv.x & 0xFFFF);
    float o1 = bf2f(o.x >> 16)    + kT2 * bf2f(vv.x >> 16);
    float o2 = bf2f(o.y & 0xFFFF) + kT2 * bf2f(vv.y & 0xFFFF);
    float o3 = bf2f(o.y >> 16)    + kT2 * bf2f(vv.y >> 16);
    *(uint2*)op = make_uint2(pack2(o0, o1), pack2(o2, o3));
  }
}

extern "C" void kernel_launch(void* const* d_in, const int* in_sizes, int n_in,
                              void* d_out, int out_size, void* d_ws, size_t ws_size,
                              hipStream_t stream) {
  const float* query  = (const float*)d_in[0];
  const float* key    = (const float*)d_in[1];
  const float* value  = (const float*)d_in[2];
  const float* qsem   = (const float*)d_in[3];
  const float* ksem   = (const float*)d_in[4];
  const float* semmap = (const float*)d_in[5];
  const float* Wi     = (const float*)d_in[6];
  const float* bi     = (const float*)d_in[7];
  const float* Wo     = (const float*)d_in[8];
  const float* bo     = (const float*)d_in[9];
  float* out = (float*)d_out;

  char* ws = (char*)d_ws;
  unsigned long long* SMASK = (unsigned long long*)ws;          ws += 1024 * 16 * 8;
  ushort* Q16  = (ushort*)ws;  ws += (size_t)64 * kSeq * kHD * 2;   // 8 MB
  ushort* K16  = (ushort*)ws;  ws += (size_t)64 * kSeq * kHD * 2;   // 8 MB
  ushort* V16  = (ushort*)ws;  ws += (size_t)64 * kSeq * kHD * 2;   // 8 MB
  ushort* MIX16 = (ushort*)ws; ws += (size_t)kSeq * kBsz * kEmb * 2; // 8 MB
  float* P1 = (float*)ws;      ws += (size_t)64 * kSeq * kHD * 4;   // 16 MB
  float* P0 = out;   // d_out is dead until the final GEMM: use as fp32 Q proj

  const dim3 gp(64, 8, 2);   // fp32 proj grid (128x64 tiles, z = q/k)
  const dim3 g3(64, 8, 3);   // bf16 gemm grid, z = qsem/ksem/value
  const dim3 gb(64, 8);      // bf16 gemm grid (out proj)
  const dim3 gs(16, 64);     // sca: t-tile x bh
  const dim3 gv(8, 64);      // ssa: 128-row t-tile x bh

  smask_prep<<<1024, 256, 0, stream>>>(semmap, SMASK);
  // SCA projections (bf16 MFMA), merged q/k/v in one launch
  gemm_bf16<<<g3, 256, 0, stream>>>(qsem, ksem, value, nullptr, Wi, bi,
                                    nullptr, Q16, 0, 0, 1, kScale);
  // SCA attention -> MIX16 = bf16(T1 * o_sca)
  sca_mfma2<<<gs, 256, 0, stream>>>(Q16, K16, V16, SMASK, MIX16);
  // SSA projections: fp32 math identical to R1 + bf16 shadows (merged q/k)
  proj_v4<<<gp, 256, 0, stream>>>(query, key, Wi, bi, P0, P1, Q16, K16);
  // SSA screen+verify -> MIX16 += bf16(T2 * v[argmax])
  ssa_v3<<<gv, 512, 0, stream>>>(Q16, K16, P0, P1, V16, SMASK, MIX16);
  // Out projection (reads bf16 MIX16 directly)
  gemm_bf16<<<gb, 256, 0, stream>>>(nullptr, nullptr, nullptr, MIX16, Wo, bo,
                                    out, nullptr, 0, 2, 0, 1.0f);
}